// Round 12
// baseline (174.213 us; speedup 1.0000x reference)
//
#include <hip/hip_runtime.h>
#include <hip/hip_bf16.h>
#include <math.h>

typedef __attribute__((ext_vector_type(8))) short short8v;
typedef __attribute__((ext_vector_type(4))) short short4v;
typedef __attribute__((ext_vector_type(4))) float float4v;

#define TB 64   // targets per block (4 waves x 16 targets)

__device__ __forceinline__ short f2bf(float f) {
    __hip_bfloat16 h = __float2bfloat16(f);
    short s; __builtin_memcpy(&s, &h, sizeof(short));
    return s;
}
__device__ __forceinline__ float bf2f(short u) {
    unsigned int x = ((unsigned int)(unsigned short)u) << 16;
    float f; __builtin_memcpy(&f, &x, sizeof(float));
    return f;
}
__device__ __forceinline__ float4v mfma_bf16(short8v a, short8v b, float4v c) {
    return __builtin_amdgcn_mfma_f32_16x16x32_bf16(a, b, c, 0, 0, 0);
}

// Copy with non-temporal load+store: this data is touched exactly once.
__global__ __launch_bounds__(256)
void copy_x_kernel(const float4v* __restrict__ x, float4v* __restrict__ out, int n4) {
    int i = blockIdx.x * blockDim.x + threadIdx.x;
    if (i < n4) {
        float4v v = __builtin_nontemporal_load(&x[i]);
        __builtin_nontemporal_store(v, &out[i]);
    }
}

// Precompute ALL MFMA weight fragments in per-lane order -> d_ws (bf16).
// 18 fragments x 64 lanes x 8 u16 = 18432 B.
//   frag 0..7  : b1 (W1), f = ct*2+kh      -> fo_w rows  0..63
//   frag 8..15 : b2 (W2), f-8 = ct*2+kh    -> fo_w rows 64..127
//   frag 16..17: smw broadcast, kh = frag&1 -> sm_w
__global__ __launch_bounds__(256)
void prep_w_kernel(const float* __restrict__ fo_w, const float* __restrict__ sm_w,
                   unsigned short* __restrict__ ws) {
    int t = blockIdx.x * 256 + threadIdx.x;
    if (t >= 18 * 64) return;
    const int frag = t >> 6, lane = t & 63;
    const int lo16 = lane & 15, g = lane >> 4;
    short8v v;
    if (frag < 16) {
        const int isB2 = frag >> 3, f = frag & 7;
        const int ct = f >> 1, kh = f & 1;
        const int kbase = isB2 * 64 + kh * 32 + g * 8;
        const int col = ct * 16 + lo16;
        #pragma unroll
        for (int j = 0; j < 8; ++j)
            v[j] = f2bf(fo_w[(size_t)(kbase + j) * 64 + col]);
    } else {
        const int kh = frag & 1;
        #pragma unroll
        for (int j = 0; j < 8; ++j)
            v[j] = f2bf(sm_w[kh * 32 + g * 8 + j]);
    }
    *(short8v*)&ws[(size_t)t * 8] = v;
}

// Block = 256 threads (4 waves), TB=64 targets; wave owns 16 targets = 128 point
// rows = 8 m-tiles. OPERAND-SWAPPED MFMA: A = weights (row = cout), B = points
// (col = point) -> dwordx4 ptx_out stores, 1 exp/lane, octet-butterfly softmax.
// Softmax: feat_px part + sm_b segment-constant -> cancel.
// ptx_out = ptx@W1 + q[t], q = fpx@W2 + fo_b.
// Weight fragments preloaded from d_ws (prep kernel); q/agg bf16 in LDS;
// LDS ~19.5KB; single barrier (all LDS wave-private after meta).
// r12: NON-TEMPORAL stores on ptx_out/xout — ptx_out (246MB, never re-read)
// was write-allocating through L3 and evicting the ptx read stream (FETCH
// showed only 50% L3 hit on reads).
// r8/r10 lesson: keep main-loop liveness at the 64-VGPR set (depth-1 prefetch,
// named regs, no deferred state) — the compiler spills anything above it.
__global__ __launch_bounds__(256, 4)
void fused_kernel(const float* __restrict__ x,
                  const float* __restrict__ ptx,
                  const unsigned short* __restrict__ ws,
                  const float* __restrict__ fo_b,
                  const int* __restrict__ point_key,
                  const int* __restrict__ pixel_tgt_idx,
                  float* __restrict__ xout,
                  float* __restrict__ ptx_out,
                  int n_tgt, int n_pts, int hw)
{
    __shared__ __align__(16) unsigned short sraw[64 * 72];
    __shared__ __align__(16) unsigned short agg_b[64][72];
    __shared__ int pix_s[TB], r0_s[TB], deg_s[TB];
    unsigned short (*fpx)[72]   = (unsigned short (*)[72])sraw;
    unsigned short (*q_lds)[72] = (unsigned short (*)[72])sraw;

    const int tid  = threadIdx.x;
    const int lane = tid & 63;
    const int w    = tid >> 6;
    const int lo16 = lane & 15;
    const int g    = lane >> 4;
    const int t0   = blockIdx.x * TB;
    const int tw0  = w * 16;              // wave's first local target

    // ---- S0: metadata — the ONLY cross-wave LDS dependency ----
    if (tid < TB) {
        int t = t0 + tid;
        bool v = t < n_tgt;
        int r0 = v ? point_key[t] : 0;
        int d  = v ? (point_key[t + 1] - r0) : 0;
        pix_s[tid] = v ? pixel_tgt_idx[t] : 0;
        r0_s[tid]  = r0;
        deg_s[tid] = d > 8 ? 8 : d;
    }
    __syncthreads();   // meta visible; everything below is wave-private

    // ---- pgm: point-row indices for all 8 m-tiles ----
    int pgm[8];
    #pragma unroll
    for (int mt = 0; mt < 8; ++mt) {
        int tlA = tw0 + mt * 2 + (lo16 >> 3);
        int pg  = r0_s[tlA] + (lo16 & 7);
        pgm[mt] = pg < n_pts ? pg : n_pts - 1;
    }

    // ---- fpx gather (4 threads/target, coalesced per channel plane) ----
    {
        const int tgt = tid >> 2, q4 = tid & 3;
        const int pix = pix_s[tgt];
        const float* xp = x + (size_t)(q4 * 16) * hw + pix;
        #pragma unroll
        for (int hhalf = 0; hhalf < 2; ++hhalf) {
            short8v pk;
            #pragma unroll
            for (int j = 0; j < 8; ++j)
                pk[j] = f2bf(xp[(size_t)(hhalf * 8 + j) * hw]);
            *(short8v*)&fpx[tgt][q4 * 16 + hhalf * 8] = pk;
        }
    }

    // ---- weight fragments from d_ws: 10x coalesced 16B loads ----
    short8v b1[5][2];
    #pragma unroll
    for (int ct = 0; ct < 4; ++ct)
        #pragma unroll
        for (int kh = 0; kh < 2; ++kh)
            b1[ct][kh] = *(const short8v*)&ws[(size_t)((ct * 2 + kh) * 64 + lane) * 8];
    #pragma unroll
    for (int kh = 0; kh < 2; ++kh)
        b1[4][kh] = *(const short8v*)&ws[(size_t)((16 + kh) * 64 + lane) * 8];

    // ---- first point-tile load, issued before q-GEMM for latency cover ----
    float4 lb0, lb1, lb2, lb3;
    {
        const float* prow = ptx + (size_t)pgm[0] * 64 + g * 8;
        lb0 = *(const float4*)(prow);
        lb1 = *(const float4*)(prow + 4);
        lb2 = *(const float4*)(prow + 32);
        lb3 = *(const float4*)(prow + 36);
    }

    // ---- q-GEMM (A = W2 from ws, B = fpx cols); wave-private fpx rows ----
    float4v qv4[4];
    {
        short8v a20 = *(const short8v*)&fpx[tw0 + lo16][g * 8];
        short8v a21 = *(const short8v*)&fpx[tw0 + lo16][32 + g * 8];
        #pragma unroll
        for (int ct = 0; ct < 4; ++ct) {
            short8v b20 = *(const short8v*)&ws[(size_t)((8 + ct * 2 + 0) * 64 + lane) * 8];
            short8v b21 = *(const short8v*)&ws[(size_t)((8 + ct * 2 + 1) * 64 + lane) * 8];
            float4v z = {0.f, 0.f, 0.f, 0.f};
            z = mfma_bf16(b20, a20, z);
            qv4[ct] = mfma_bf16(b21, a21, z);
        }
    }
    // park q as bf16 over fpx (wave-private rows; ds ops in wave order)
    {
        float4 fb40 = *(const float4*)&fo_b[ 0 + g * 4];
        float4 fb41 = *(const float4*)&fo_b[16 + g * 4];
        float4 fb42 = *(const float4*)&fo_b[32 + g * 4];
        float4 fb43 = *(const float4*)&fo_b[48 + g * 4];
        short4v q0, q1, q2, q3;
        q0[0] = f2bf(qv4[0][0] + fb40.x); q0[1] = f2bf(qv4[0][1] + fb40.y);
        q0[2] = f2bf(qv4[0][2] + fb40.z); q0[3] = f2bf(qv4[0][3] + fb40.w);
        q1[0] = f2bf(qv4[1][0] + fb41.x); q1[1] = f2bf(qv4[1][1] + fb41.y);
        q1[2] = f2bf(qv4[1][2] + fb41.z); q1[3] = f2bf(qv4[1][3] + fb41.w);
        q2[0] = f2bf(qv4[2][0] + fb42.x); q2[1] = f2bf(qv4[2][1] + fb42.y);
        q2[2] = f2bf(qv4[2][2] + fb42.z); q2[3] = f2bf(qv4[2][3] + fb42.w);
        q3[0] = f2bf(qv4[3][0] + fb43.x); q3[1] = f2bf(qv4[3][1] + fb43.y);
        q3[2] = f2bf(qv4[3][2] + fb43.z); q3[3] = f2bf(qv4[3][3] + fb43.w);
        *(short4v*)&q_lds[tw0 + lo16][ 0 + g * 4] = q0;
        *(short4v*)&q_lds[tw0 + lo16][16 + g * 4] = q1;
        *(short4v*)&q_lds[tw0 + lo16][32 + g * 4] = q2;
        *(short4v*)&q_lds[tw0 + lo16][48 + g * 4] = q3;
    }

// per-channel-tile epilogue on NAMED regs; NON-TEMPORAL ptx_out store
#define EPIL_CT(CT, CREG)                                                      \
    {                                                                          \
        const int colb = (CT) * 16 + g * 4;                                    \
        const short4v qb = *(const short4v*)&q_lds[tE][colb];                  \
        float4v po;                                                            \
        po[0] = CREG[0] + bf2f(qb[0]); po[1] = CREG[1] + bf2f(qb[1]);          \
        po[2] = CREG[2] + bf2f(qb[2]); po[3] = CREG[3] + bf2f(qb[3]);          \
        if (val)                                                               \
            __builtin_nontemporal_store(po,                                    \
                (float4v*)&ptx_out[(size_t)(r0E + pE) * 64 + colb]);           \
        float s0 = po[0] * wn, s1 = po[1] * wn, s2 = po[2] * wn, s3 = po[3] * wn; \
        s0 += __shfl_xor(s0, 1); s1 += __shfl_xor(s1, 1);                      \
        s2 += __shfl_xor(s2, 1); s3 += __shfl_xor(s3, 1);                      \
        s0 += __shfl_xor(s0, 2); s1 += __shfl_xor(s1, 2);                      \
        s2 += __shfl_xor(s2, 2); s3 += __shfl_xor(s3, 2);                      \
        s0 += __shfl_xor(s0, 4); s1 += __shfl_xor(s1, 4);                      \
        s2 += __shfl_xor(s2, 4); s3 += __shfl_xor(s3, 4);                      \
        if (pE == 0) {                                                         \
            short4v ag;                                                        \
            ag[0] = f2bf(s0); ag[1] = f2bf(s1);                                \
            ag[2] = f2bf(s2); ag[3] = f2bf(s3);                                \
            *(short4v*)&agg_b[tE][colb] = ag;                                  \
        }                                                                      \
    }

    // ---- main loop: 8 m-tiles, depth-1 prefetch, inline epilogue ----
    #pragma unroll
    for (int mt = 0; mt < 8; ++mt) {
        short8v a0, a1;   // B operand: col = point
        a0[0] = f2bf(lb0.x); a0[1] = f2bf(lb0.y); a0[2] = f2bf(lb0.z); a0[3] = f2bf(lb0.w);
        a0[4] = f2bf(lb1.x); a0[5] = f2bf(lb1.y); a0[6] = f2bf(lb1.z); a0[7] = f2bf(lb1.w);
        a1[0] = f2bf(lb2.x); a1[1] = f2bf(lb2.y); a1[2] = f2bf(lb2.z); a1[3] = f2bf(lb2.w);
        a1[4] = f2bf(lb3.x); a1[5] = f2bf(lb3.y); a1[6] = f2bf(lb3.z); a1[7] = f2bf(lb3.w);

        if (mt < 7) {   // prefetch next tile
            const float* prow = ptx + (size_t)pgm[mt + 1] * 64 + g * 8;
            lb0 = *(const float4*)(prow);
            lb1 = *(const float4*)(prow + 4);
            lb2 = *(const float4*)(prow + 32);
            lb3 = *(const float4*)(prow + 36);
        }

        float4v z = {0.f, 0.f, 0.f, 0.f};
        float4v cc0 = mfma_bf16(b1[0][1], a1, mfma_bf16(b1[0][0], a0, z));
        float4v cc1 = mfma_bf16(b1[1][1], a1, mfma_bf16(b1[1][0], a0, z));
        float4v cc2 = mfma_bf16(b1[2][1], a1, mfma_bf16(b1[2][0], a0, z));
        float4v cc3 = mfma_bf16(b1[3][1], a1, mfma_bf16(b1[3][0], a0, z));
        float4v cc4 = mfma_bf16(b1[4][1], a1, mfma_bf16(b1[4][0], a0, z));

        // lane owns point pE of target tE; logit = cc4[0] (rows identical)
        const int tE   = tw0 + mt * 2 + (lo16 >> 3);
        const int degE = deg_s[tE];
        const int r0E  = r0_s[tE];
        const int pE   = lo16 & 7;
        const bool val = (pE < degE);

        float lg = val ? cc4[0] : -3.4e38f;
        float mx = lg;
        mx = fmaxf(mx, __shfl_xor(mx, 1));
        mx = fmaxf(mx, __shfl_xor(mx, 2));
        mx = fmaxf(mx, __shfl_xor(mx, 4));
        float e = val ? __expf(lg - mx) : 0.0f;
        float sm = e;
        sm += __shfl_xor(sm, 1);
        sm += __shfl_xor(sm, 2);
        sm += __shfl_xor(sm, 4);
        const float wn = e / (sm + 1e-16f);

        EPIL_CT(0, cc0)
        EPIL_CT(1, cc1)
        EPIL_CT(2, cc2)
        EPIL_CT(3, cc3)
    }
#undef EPIL_CT

    // ---- xout write-back: wave-private agg rows, non-temporal stores ----
    {
        const int tgt = tid >> 2, q4 = tid & 3;
        if (t0 + tgt < n_tgt) {
            const int pix = pix_s[tgt];
            float* xp = xout + (size_t)(q4 * 16) * hw + pix;
            #pragma unroll
            for (int u = 0; u < 4; ++u) {
                short4v v = *(const short4v*)&agg_b[tgt][q4 * 16 + u * 4];
                __builtin_nontemporal_store(bf2f(v[0]), &xp[(size_t)(u * 4 + 0) * hw]);
                __builtin_nontemporal_store(bf2f(v[1]), &xp[(size_t)(u * 4 + 1) * hw]);
                __builtin_nontemporal_store(bf2f(v[2]), &xp[(size_t)(u * 4 + 2) * hw]);
                __builtin_nontemporal_store(bf2f(v[3]), &xp[(size_t)(u * 4 + 3) * hw]);
            }
        }
    }
}

extern "C" void kernel_launch(void* const* d_in, const int* in_sizes, int n_in,
                              void* d_out, int out_size, void* d_ws, size_t ws_size,
                              hipStream_t stream) {
    const float* x             = (const float*)d_in[0];
    const float* ptx           = (const float*)d_in[1];
    const float* sm_w          = (const float*)d_in[2];
    // d_in[3] = sm_b: segment-constant logit shift, cancels in softmax
    const float* fo_w          = (const float*)d_in[4];
    const float* fo_b          = (const float*)d_in[5];
    const int*   point_key     = (const int*)d_in[6];
    const int*   pixel_tgt_idx = (const int*)d_in[7];

    const int x_elems = in_sizes[0];          // 64 * H * W
    const int hw      = x_elems / 64;
    const int n_tgt   = in_sizes[7];
    const int n_pts   = in_sizes[1] / 64;

    float* xout    = (float*)d_out;
    float* ptx_out = xout + (size_t)x_elems;

    const int n4 = x_elems / 4;
    copy_x_kernel<<<(n4 + 255) / 256, 256, 0, stream>>>(
        (const float4v*)x, (float4v*)xout, n4);

    prep_w_kernel<<<5, 256, 0, stream>>>(fo_w, sm_w, (unsigned short*)d_ws);

    const int blocks = (n_tgt + TB - 1) / TB;
    fused_kernel<<<blocks, 256, 0, stream>>>(
        x, ptx, (const unsigned short*)d_ws, fo_b, point_key, pixel_tgt_idx,
        xout, ptx_out, n_tgt, n_pts, hw);
}

// Round 13
// 140.922 us; speedup vs baseline: 1.2362x; 1.2362x over previous
//
#include <hip/hip_runtime.h>
#include <hip/hip_bf16.h>
#include <math.h>

typedef __attribute__((ext_vector_type(8))) short short8v;
typedef __attribute__((ext_vector_type(4))) short short4v;
typedef __attribute__((ext_vector_type(4))) float float4v;

#define TB 64            // targets per fused block (4 waves x 16 targets)
#define WS_MASK_OFF 32768

__device__ __forceinline__ short f2bf(float f) {
    __hip_bfloat16 h = __float2bfloat16(f);
    short s; __builtin_memcpy(&s, &h, sizeof(short));
    return s;
}
__device__ __forceinline__ float bf2f(short u) {
    unsigned int x = ((unsigned int)(unsigned short)u) << 16;
    float f; __builtin_memcpy(&f, &x, sizeof(float));
    return f;
}
__device__ __forceinline__ float4v mfma_bf16(short8v a, short8v b, float4v c) {
    return __builtin_amdgcn_mfma_f32_16x16x32_bf16(a, b, c, 0, 0, 0);
}

__global__ __launch_bounds__(256)
void mask_set_kernel(const int* __restrict__ idx, unsigned char* __restrict__ mask, int n) {
    int i = blockIdx.x * blockDim.x + threadIdx.x;
    if (i < n) mask[idx[i]] = 1;
}

// Fallback full copy (used only if d_ws is too small for the mask).
__global__ __launch_bounds__(256)
void copy_x_kernel(const float4v* __restrict__ x, float4v* __restrict__ out, int n4) {
    int i = blockIdx.x * blockDim.x + threadIdx.x;
    if (i < n4) out[i] = x[i];
}

// Precompute ALL MFMA weight fragments in per-lane order -> d_ws (bf16).
// 18 fragments x 64 lanes x 8 u16 = 18432 B (mask lives at WS_MASK_OFF).
//   frag 0..7  : b1 (W1), f = ct*2+kh      -> fo_w rows  0..63
//   frag 8..15 : b2 (W2), f-8 = ct*2+kh    -> fo_w rows 64..127
//   frag 16..17: smw broadcast, kh = frag&1 -> sm_w
__global__ __launch_bounds__(256)
void prep_w_kernel(const float* __restrict__ fo_w, const float* __restrict__ sm_w,
                   unsigned short* __restrict__ ws) {
    int t = blockIdx.x * 256 + threadIdx.x;
    if (t >= 18 * 64) return;
    const int frag = t >> 6, lane = t & 63;
    const int lo16 = lane & 15, g = lane >> 4;
    short8v v;
    if (frag < 16) {
        const int isB2 = frag >> 3, f = frag & 7;
        const int ct = f >> 1, kh = f & 1;
        const int kbase = isB2 * 64 + kh * 32 + g * 8;
        const int col = ct * 16 + lo16;
        #pragma unroll
        for (int j = 0; j < 8; ++j)
            v[j] = f2bf(fo_w[(size_t)(kbase + j) * 64 + col]);
    } else {
        const int kh = frag & 1;
        #pragma unroll
        for (int j = 0; j < 8; ++j)
            v[j] = f2bf(sm_w[kh * 32 + g * 8 + j]);
    }
    *(short8v*)&ws[(size_t)t * 8] = v;
}

// MERGED kernel: blocks [0, fusedBlocks) run the fused segment-softmax+MLP;
// blocks [fusedBlocks, ...) copy x->xout for NON-covered pixel quads (mask).
// Copy work overlaps fused's latency bubbles on the same CUs (r13).
// Fused structure (r7/r11, best at ~137us): OPERAND-SWAPPED MFMA (A=weights,
// B=points -> lane holds 4 consecutive channels of ONE point: dwordx4 stores,
// 1 exp/lane, octet-butterfly softmax). feat_px logit part + sm_b cancel in
// segment softmax. ptx_out = ptx@W1 + q[t], q = fpx@W2 + fo_b (bf16 in LDS).
// r8/r10: keep main-loop liveness at the 64-VGPR set. r12: NO nontemporal
// stores (evict-first amplified partial-line writebacks: WRITE +70MB).
__global__ __launch_bounds__(256, 4)
void fused_kernel(const float* __restrict__ x,
                  const float* __restrict__ ptx,
                  const unsigned short* __restrict__ ws,
                  const float* __restrict__ fo_b,
                  const int* __restrict__ point_key,
                  const int* __restrict__ pixel_tgt_idx,
                  float* __restrict__ xout,
                  float* __restrict__ ptx_out,
                  const unsigned int* __restrict__ mask4,
                  int n_tgt, int n_pts, int hw, int q4n, int fusedBlocks)
{
    __shared__ __align__(16) unsigned short sraw[64 * 72];
    __shared__ __align__(16) unsigned short agg_b[64][72];
    __shared__ int pix_s[TB], r0_s[TB], deg_s[TB];
    unsigned short (*fpx)[72]   = (unsigned short (*)[72])sraw;
    unsigned short (*q_lds)[72] = (unsigned short (*)[72])sraw;

    const int tid = threadIdx.x;

    // ---- copy blocks: masked x->xout for uncovered quads (overlaps fused) ----
    if ((int)blockIdx.x >= fusedBlocks) {
        const int i = (blockIdx.x - fusedBlocks) * 256 + tid;
        if (i < q4n && mask4[i] != 0x01010101u) {
            const float4v* x4 = (const float4v*)x;
            float4v* o4 = (float4v*)xout;
            #pragma unroll 4
            for (int c = 0; c < 64; ++c)
                o4[(size_t)c * q4n + i] = x4[(size_t)c * q4n + i];
        }
        return;
    }

    const int lane = tid & 63;
    const int w    = tid >> 6;
    const int lo16 = lane & 15;
    const int g    = lane >> 4;
    const int t0   = blockIdx.x * TB;
    const int tw0  = w * 16;              // wave's first local target

    // ---- S0: metadata — the ONLY cross-wave LDS dependency ----
    if (tid < TB) {
        int t = t0 + tid;
        bool v = t < n_tgt;
        int r0 = v ? point_key[t] : 0;
        int d  = v ? (point_key[t + 1] - r0) : 0;
        pix_s[tid] = v ? pixel_tgt_idx[t] : 0;
        r0_s[tid]  = r0;
        deg_s[tid] = d > 8 ? 8 : d;
    }
    __syncthreads();   // meta visible; everything below is wave-private

    // ---- pgm: point-row indices for all 8 m-tiles ----
    int pgm[8];
    #pragma unroll
    for (int mt = 0; mt < 8; ++mt) {
        int tlA = tw0 + mt * 2 + (lo16 >> 3);
        int pg  = r0_s[tlA] + (lo16 & 7);
        pgm[mt] = pg < n_pts ? pg : n_pts - 1;
    }

    // ---- fpx gather (4 threads/target, coalesced per channel plane) ----
    {
        const int tgt = tid >> 2, q4 = tid & 3;
        const int pix = pix_s[tgt];
        const float* xp = x + (size_t)(q4 * 16) * hw + pix;
        #pragma unroll
        for (int hhalf = 0; hhalf < 2; ++hhalf) {
            short8v pk;
            #pragma unroll
            for (int j = 0; j < 8; ++j)
                pk[j] = f2bf(xp[(size_t)(hhalf * 8 + j) * hw]);
            *(short8v*)&fpx[tgt][q4 * 16 + hhalf * 8] = pk;
        }
    }

    // ---- weight fragments from d_ws: 10x coalesced 16B loads ----
    short8v b1[5][2];
    #pragma unroll
    for (int ct = 0; ct < 4; ++ct)
        #pragma unroll
        for (int kh = 0; kh < 2; ++kh)
            b1[ct][kh] = *(const short8v*)&ws[(size_t)((ct * 2 + kh) * 64 + lane) * 8];
    #pragma unroll
    for (int kh = 0; kh < 2; ++kh)
        b1[4][kh] = *(const short8v*)&ws[(size_t)((16 + kh) * 64 + lane) * 8];

    // ---- first point-tile load, issued before q-GEMM for latency cover ----
    float4 lb0, lb1, lb2, lb3;
    {
        const float* prow = ptx + (size_t)pgm[0] * 64 + g * 8;
        lb0 = *(const float4*)(prow);
        lb1 = *(const float4*)(prow + 4);
        lb2 = *(const float4*)(prow + 32);
        lb3 = *(const float4*)(prow + 36);
    }

    // ---- q-GEMM (A = W2 from ws, B = fpx cols); wave-private fpx rows ----
    float4v qv4[4];
    {
        short8v a20 = *(const short8v*)&fpx[tw0 + lo16][g * 8];
        short8v a21 = *(const short8v*)&fpx[tw0 + lo16][32 + g * 8];
        #pragma unroll
        for (int ct = 0; ct < 4; ++ct) {
            short8v b20 = *(const short8v*)&ws[(size_t)((8 + ct * 2 + 0) * 64 + lane) * 8];
            short8v b21 = *(const short8v*)&ws[(size_t)((8 + ct * 2 + 1) * 64 + lane) * 8];
            float4v z = {0.f, 0.f, 0.f, 0.f};
            z = mfma_bf16(b20, a20, z);
            qv4[ct] = mfma_bf16(b21, a21, z);
        }
    }
    // park q as bf16 over fpx (wave-private rows; ds ops in wave order)
    {
        float4 fb40 = *(const float4*)&fo_b[ 0 + g * 4];
        float4 fb41 = *(const float4*)&fo_b[16 + g * 4];
        float4 fb42 = *(const float4*)&fo_b[32 + g * 4];
        float4 fb43 = *(const float4*)&fo_b[48 + g * 4];
        short4v q0, q1, q2, q3;
        q0[0] = f2bf(qv4[0][0] + fb40.x); q0[1] = f2bf(qv4[0][1] + fb40.y);
        q0[2] = f2bf(qv4[0][2] + fb40.z); q0[3] = f2bf(qv4[0][3] + fb40.w);
        q1[0] = f2bf(qv4[1][0] + fb41.x); q1[1] = f2bf(qv4[1][1] + fb41.y);
        q1[2] = f2bf(qv4[1][2] + fb41.z); q1[3] = f2bf(qv4[1][3] + fb41.w);
        q2[0] = f2bf(qv4[2][0] + fb42.x); q2[1] = f2bf(qv4[2][1] + fb42.y);
        q2[2] = f2bf(qv4[2][2] + fb42.z); q2[3] = f2bf(qv4[2][3] + fb42.w);
        q3[0] = f2bf(qv4[3][0] + fb43.x); q3[1] = f2bf(qv4[3][1] + fb43.y);
        q3[2] = f2bf(qv4[3][2] + fb43.z); q3[3] = f2bf(qv4[3][3] + fb43.w);
        *(short4v*)&q_lds[tw0 + lo16][ 0 + g * 4] = q0;
        *(short4v*)&q_lds[tw0 + lo16][16 + g * 4] = q1;
        *(short4v*)&q_lds[tw0 + lo16][32 + g * 4] = q2;
        *(short4v*)&q_lds[tw0 + lo16][48 + g * 4] = q3;
    }

// per-channel-tile epilogue on NAMED regs (no arrays -> no scratch)
#define EPIL_CT(CT, CREG)                                                      \
    {                                                                          \
        const int colb = (CT) * 16 + g * 4;                                    \
        const short4v qb = *(const short4v*)&q_lds[tE][colb];                  \
        float4v po;                                                            \
        po[0] = CREG[0] + bf2f(qb[0]); po[1] = CREG[1] + bf2f(qb[1]);          \
        po[2] = CREG[2] + bf2f(qb[2]); po[3] = CREG[3] + bf2f(qb[3]);          \
        if (val)                                                               \
            *(float4v*)&ptx_out[(size_t)(r0E + pE) * 64 + colb] = po;          \
        float s0 = po[0] * wn, s1 = po[1] * wn, s2 = po[2] * wn, s3 = po[3] * wn; \
        s0 += __shfl_xor(s0, 1); s1 += __shfl_xor(s1, 1);                      \
        s2 += __shfl_xor(s2, 1); s3 += __shfl_xor(s3, 1);                      \
        s0 += __shfl_xor(s0, 2); s1 += __shfl_xor(s1, 2);                      \
        s2 += __shfl_xor(s2, 2); s3 += __shfl_xor(s3, 2);                      \
        s0 += __shfl_xor(s0, 4); s1 += __shfl_xor(s1, 4);                      \
        s2 += __shfl_xor(s2, 4); s3 += __shfl_xor(s3, 4);                      \
        if (pE == 0) {                                                         \
            short4v ag;                                                        \
            ag[0] = f2bf(s0); ag[1] = f2bf(s1);                                \
            ag[2] = f2bf(s2); ag[3] = f2bf(s3);                                \
            *(short4v*)&agg_b[tE][colb] = ag;                                  \
        }                                                                      \
    }

    // ---- main loop: 8 m-tiles, depth-1 prefetch, inline epilogue ----
    #pragma unroll
    for (int mt = 0; mt < 8; ++mt) {
        short8v a0, a1;   // B operand: col = point
        a0[0] = f2bf(lb0.x); a0[1] = f2bf(lb0.y); a0[2] = f2bf(lb0.z); a0[3] = f2bf(lb0.w);
        a0[4] = f2bf(lb1.x); a0[5] = f2bf(lb1.y); a0[6] = f2bf(lb1.z); a0[7] = f2bf(lb1.w);
        a1[0] = f2bf(lb2.x); a1[1] = f2bf(lb2.y); a1[2] = f2bf(lb2.z); a1[3] = f2bf(lb2.w);
        a1[4] = f2bf(lb3.x); a1[5] = f2bf(lb3.y); a1[6] = f2bf(lb3.z); a1[7] = f2bf(lb3.w);

        if (mt < 7) {   // prefetch next tile
            const float* prow = ptx + (size_t)pgm[mt + 1] * 64 + g * 8;
            lb0 = *(const float4*)(prow);
            lb1 = *(const float4*)(prow + 4);
            lb2 = *(const float4*)(prow + 32);
            lb3 = *(const float4*)(prow + 36);
        }

        float4v z = {0.f, 0.f, 0.f, 0.f};
        float4v cc0 = mfma_bf16(b1[0][1], a1, mfma_bf16(b1[0][0], a0, z));
        float4v cc1 = mfma_bf16(b1[1][1], a1, mfma_bf16(b1[1][0], a0, z));
        float4v cc2 = mfma_bf16(b1[2][1], a1, mfma_bf16(b1[2][0], a0, z));
        float4v cc3 = mfma_bf16(b1[3][1], a1, mfma_bf16(b1[3][0], a0, z));
        float4v cc4 = mfma_bf16(b1[4][1], a1, mfma_bf16(b1[4][0], a0, z));

        // lane owns point pE of target tE; logit = cc4[0] (rows identical)
        const int tE   = tw0 + mt * 2 + (lo16 >> 3);
        const int degE = deg_s[tE];
        const int r0E  = r0_s[tE];
        const int pE   = lo16 & 7;
        const bool val = (pE < degE);

        float lg = val ? cc4[0] : -3.4e38f;
        float mx = lg;
        mx = fmaxf(mx, __shfl_xor(mx, 1));
        mx = fmaxf(mx, __shfl_xor(mx, 2));
        mx = fmaxf(mx, __shfl_xor(mx, 4));
        float e = val ? __expf(lg - mx) : 0.0f;
        float sm = e;
        sm += __shfl_xor(sm, 1);
        sm += __shfl_xor(sm, 2);
        sm += __shfl_xor(sm, 4);
        const float wn = e / (sm + 1e-16f);

        EPIL_CT(0, cc0)
        EPIL_CT(1, cc1)
        EPIL_CT(2, cc2)
        EPIL_CT(3, cc3)
    }
#undef EPIL_CT

    // ---- xout write-back: agg rows wave-private -> no barrier ----
    {
        const int tgt = tid >> 2, q4 = tid & 3;
        if (t0 + tgt < n_tgt) {
            const int pix = pix_s[tgt];
            float* xp = xout + (size_t)(q4 * 16) * hw + pix;
            #pragma unroll
            for (int u = 0; u < 4; ++u) {
                short4v v = *(const short4v*)&agg_b[tgt][q4 * 16 + u * 4];
                xp[(size_t)(u * 4 + 0) * hw] = bf2f(v[0]);
                xp[(size_t)(u * 4 + 1) * hw] = bf2f(v[1]);
                xp[(size_t)(u * 4 + 2) * hw] = bf2f(v[2]);
                xp[(size_t)(u * 4 + 3) * hw] = bf2f(v[3]);
            }
        }
    }
}

extern "C" void kernel_launch(void* const* d_in, const int* in_sizes, int n_in,
                              void* d_out, int out_size, void* d_ws, size_t ws_size,
                              hipStream_t stream) {
    const float* x             = (const float*)d_in[0];
    const float* ptx           = (const float*)d_in[1];
    const float* sm_w          = (const float*)d_in[2];
    // d_in[3] = sm_b: segment-constant logit shift, cancels in softmax
    const float* fo_w          = (const float*)d_in[4];
    const float* fo_b          = (const float*)d_in[5];
    const int*   point_key     = (const int*)d_in[6];
    const int*   pixel_tgt_idx = (const int*)d_in[7];

    const int x_elems = in_sizes[0];          // 64 * H * W
    const int hw      = x_elems / 64;
    const int n_tgt   = in_sizes[7];
    const int n_pts   = in_sizes[1] / 64;

    float* xout    = (float*)d_out;
    float* ptx_out = xout + (size_t)x_elems;

    prep_w_kernel<<<5, 256, 0, stream>>>(fo_w, sm_w, (unsigned short*)d_ws);

    const int fusedBlocks = (n_tgt + TB - 1) / TB;
    const int q4n = hw / 4;
    const bool maskOK = (ws_size >= (size_t)WS_MASK_OFF + (size_t)hw) && ((hw & 3) == 0);

    if (maskOK) {
        unsigned char* mask = (unsigned char*)d_ws + WS_MASK_OFF;
        hipMemsetAsync(mask, 0, (size_t)hw, stream);
        mask_set_kernel<<<(n_tgt + 255) / 256, 256, 0, stream>>>(
            pixel_tgt_idx, mask, n_tgt);
        const int copyBlocks = (q4n + 255) / 256;
        fused_kernel<<<fusedBlocks + copyBlocks, 256, 0, stream>>>(
            x, ptx, (const unsigned short*)d_ws, fo_b, point_key, pixel_tgt_idx,
            xout, ptx_out, (const unsigned int*)mask,
            n_tgt, n_pts, hw, q4n, fusedBlocks);
    } else {
        const int n4 = x_elems / 4;
        copy_x_kernel<<<(n4 + 255) / 256, 256, 0, stream>>>(
            (const float4v*)x, (float4v*)xout, n4);
        fused_kernel<<<fusedBlocks, 256, 0, stream>>>(
            x, ptx, (const unsigned short*)d_ws, fo_b, point_key, pixel_tgt_idx,
            xout, ptx_out, (const unsigned int*)d_ws,
            n_tgt, n_pts, hw, q4n, fusedBlocks);
    }
}

// Round 14
// 140.589 us; speedup vs baseline: 1.2392x; 1.0024x over previous
//
#include <hip/hip_runtime.h>
#include <hip/hip_bf16.h>
#include <math.h>

typedef __attribute__((ext_vector_type(8))) short short8v;
typedef __attribute__((ext_vector_type(4))) short short4v;
typedef __attribute__((ext_vector_type(4))) float float4v;

#define TB 64            // targets per fused block (4 waves x 16 targets)
#define WS_MASK_OFF 32768

__device__ __forceinline__ short f2bf(float f) {
    __hip_bfloat16 h = __float2bfloat16(f);
    short s; __builtin_memcpy(&s, &h, sizeof(short));
    return s;
}
__device__ __forceinline__ float bf2f(short u) {
    unsigned int x = ((unsigned int)(unsigned short)u) << 16;
    float f; __builtin_memcpy(&f, &x, sizeof(float));
    return f;
}
__device__ __forceinline__ float4v mfma_bf16(short8v a, short8v b, float4v c) {
    return __builtin_amdgcn_mfma_f32_16x16x32_bf16(a, b, c, 0, 0, 0);
}

__global__ __launch_bounds__(256)
void mask_set_kernel(const int* __restrict__ idx, unsigned char* __restrict__ mask, int n) {
    int i = blockIdx.x * blockDim.x + threadIdx.x;
    if (i < n) mask[idx[i]] = 1;
}

// Fallback full copy (used only if d_ws is too small for the mask).
__global__ __launch_bounds__(256)
void copy_x_kernel(const float4v* __restrict__ x, float4v* __restrict__ out, int n4) {
    int i = blockIdx.x * blockDim.x + threadIdx.x;
    if (i < n4) out[i] = x[i];
}

// Precompute ALL MFMA weight fragments in per-lane order -> d_ws (bf16).
// 18 fragments x 64 lanes x 8 u16 = 18432 B (mask lives at WS_MASK_OFF).
__global__ __launch_bounds__(256)
void prep_w_kernel(const float* __restrict__ fo_w, const float* __restrict__ sm_w,
                   unsigned short* __restrict__ ws) {
    int t = blockIdx.x * 256 + threadIdx.x;
    if (t >= 18 * 64) return;
    const int frag = t >> 6, lane = t & 63;
    const int lo16 = lane & 15, g = lane >> 4;
    short8v v;
    if (frag < 16) {
        const int isB2 = frag >> 3, f = frag & 7;
        const int ct = f >> 1, kh = f & 1;
        const int kbase = isB2 * 64 + kh * 32 + g * 8;
        const int col = ct * 16 + lo16;
        #pragma unroll
        for (int j = 0; j < 8; ++j)
            v[j] = f2bf(fo_w[(size_t)(kbase + j) * 64 + col]);
    } else {
        const int kh = frag & 1;
        #pragma unroll
        for (int j = 0; j < 8; ++j)
            v[j] = f2bf(sm_w[kh * 32 + g * 8 + j]);
    }
    *(short8v*)&ws[(size_t)t * 8] = v;
}

// MERGED kernel: blocks [0, fusedBlocks) = fused segment-softmax+MLP;
// blocks >= fusedBlocks copy x->xout for NON-covered pixel quads.
// r14: __launch_bounds__(256) with NO min-waves arg — the (256,4) clamp
// appears to have pinned residency at 4 blocks/CU (r12: 19.4KB LDS + 60 VGPR
// yet OccupancyPercent stayed 38%), nullifying every occupancy experiment.
// Fused structure (r7 best): OPERAND-SWAPPED MFMA (A=weights, B=points ->
// lane holds 4 consecutive channels of ONE point: dwordx4 stores, 1 exp/lane,
// octet-butterfly softmax). feat_px logit part + sm_b cancel in segment
// softmax. ptx_out = ptx@W1 + q[t], q = fpx@W2 + fo_b (bf16 in LDS).
// r8/r10: keep main-loop liveness near 64 VGPR. r12: no nontemporal stores.
__global__ __launch_bounds__(256)
void fused_kernel(const float* __restrict__ x,
                  const float* __restrict__ ptx,
                  const unsigned short* __restrict__ ws,
                  const float* __restrict__ fo_b,
                  const int* __restrict__ point_key,
                  const int* __restrict__ pixel_tgt_idx,
                  float* __restrict__ xout,
                  float* __restrict__ ptx_out,
                  const unsigned int* __restrict__ mask4,
                  int n_tgt, int n_pts, int hw, int q4n, int fusedBlocks)
{
    __shared__ __align__(16) unsigned short sraw[64 * 72];
    __shared__ __align__(16) unsigned short agg_b[64][72];
    __shared__ int pix_s[TB], r0_s[TB], deg_s[TB];
    unsigned short (*fpx)[72]   = (unsigned short (*)[72])sraw;
    unsigned short (*q_lds)[72] = (unsigned short (*)[72])sraw;

    const int tid = threadIdx.x;

    // ---- copy blocks: masked x->xout for uncovered quads (overlaps fused) ----
    if ((int)blockIdx.x >= fusedBlocks) {
        const int i = (blockIdx.x - fusedBlocks) * 256 + tid;
        if (i < q4n && mask4[i] != 0x01010101u) {
            const float4v* x4 = (const float4v*)x;
            float4v* o4 = (float4v*)xout;
            #pragma unroll 4
            for (int c = 0; c < 64; ++c)
                o4[(size_t)c * q4n + i] = x4[(size_t)c * q4n + i];
        }
        return;
    }

    const int lane = tid & 63;
    const int w    = tid >> 6;
    const int lo16 = lane & 15;
    const int g    = lane >> 4;
    const int t0   = blockIdx.x * TB;
    const int tw0  = w * 16;              // wave's first local target

    // ---- S0: metadata — the ONLY cross-wave LDS dependency ----
    if (tid < TB) {
        int t = t0 + tid;
        bool v = t < n_tgt;
        int r0 = v ? point_key[t] : 0;
        int d  = v ? (point_key[t + 1] - r0) : 0;
        pix_s[tid] = v ? pixel_tgt_idx[t] : 0;
        r0_s[tid]  = r0;
        deg_s[tid] = d > 8 ? 8 : d;
    }
    __syncthreads();   // meta visible; everything below is wave-private

    // ---- pgm: point-row indices for all 8 m-tiles ----
    int pgm[8];
    #pragma unroll
    for (int mt = 0; mt < 8; ++mt) {
        int tlA = tw0 + mt * 2 + (lo16 >> 3);
        int pg  = r0_s[tlA] + (lo16 & 7);
        pgm[mt] = pg < n_pts ? pg : n_pts - 1;
    }

    // ---- fpx gather (4 threads/target, coalesced per channel plane) ----
    {
        const int tgt = tid >> 2, q4 = tid & 3;
        const int pix = pix_s[tgt];
        const float* xp = x + (size_t)(q4 * 16) * hw + pix;
        #pragma unroll
        for (int hhalf = 0; hhalf < 2; ++hhalf) {
            short8v pk;
            #pragma unroll
            for (int j = 0; j < 8; ++j)
                pk[j] = f2bf(xp[(size_t)(hhalf * 8 + j) * hw]);
            *(short8v*)&fpx[tgt][q4 * 16 + hhalf * 8] = pk;
        }
    }

    // ---- weight fragments from d_ws: 10x coalesced 16B loads ----
    short8v b1[5][2];
    #pragma unroll
    for (int ct = 0; ct < 4; ++ct)
        #pragma unroll
        for (int kh = 0; kh < 2; ++kh)
            b1[ct][kh] = *(const short8v*)&ws[(size_t)((ct * 2 + kh) * 64 + lane) * 8];
    #pragma unroll
    for (int kh = 0; kh < 2; ++kh)
        b1[4][kh] = *(const short8v*)&ws[(size_t)((16 + kh) * 64 + lane) * 8];

    // ---- first point-tile load, issued before q-GEMM for latency cover ----
    float4 lb0, lb1, lb2, lb3;
    {
        const float* prow = ptx + (size_t)pgm[0] * 64 + g * 8;
        lb0 = *(const float4*)(prow);
        lb1 = *(const float4*)(prow + 4);
        lb2 = *(const float4*)(prow + 32);
        lb3 = *(const float4*)(prow + 36);
    }

    // ---- q-GEMM (A = W2 from ws, B = fpx cols); wave-private fpx rows ----
    float4v qv4[4];
    {
        short8v a20 = *(const short8v*)&fpx[tw0 + lo16][g * 8];
        short8v a21 = *(const short8v*)&fpx[tw0 + lo16][32 + g * 8];
        #pragma unroll
        for (int ct = 0; ct < 4; ++ct) {
            short8v b20 = *(const short8v*)&ws[(size_t)((8 + ct * 2 + 0) * 64 + lane) * 8];
            short8v b21 = *(const short8v*)&ws[(size_t)((8 + ct * 2 + 1) * 64 + lane) * 8];
            float4v z = {0.f, 0.f, 0.f, 0.f};
            z = mfma_bf16(b20, a20, z);
            qv4[ct] = mfma_bf16(b21, a21, z);
        }
    }
    // park q as bf16 over fpx (wave-private rows; ds ops in wave order)
    {
        float4 fb40 = *(const float4*)&fo_b[ 0 + g * 4];
        float4 fb41 = *(const float4*)&fo_b[16 + g * 4];
        float4 fb42 = *(const float4*)&fo_b[32 + g * 4];
        float4 fb43 = *(const float4*)&fo_b[48 + g * 4];
        short4v q0, q1, q2, q3;
        q0[0] = f2bf(qv4[0][0] + fb40.x); q0[1] = f2bf(qv4[0][1] + fb40.y);
        q0[2] = f2bf(qv4[0][2] + fb40.z); q0[3] = f2bf(qv4[0][3] + fb40.w);
        q1[0] = f2bf(qv4[1][0] + fb41.x); q1[1] = f2bf(qv4[1][1] + fb41.y);
        q1[2] = f2bf(qv4[1][2] + fb41.z); q1[3] = f2bf(qv4[1][3] + fb41.w);
        q2[0] = f2bf(qv4[2][0] + fb42.x); q2[1] = f2bf(qv4[2][1] + fb42.y);
        q2[2] = f2bf(qv4[2][2] + fb42.z); q2[3] = f2bf(qv4[2][3] + fb42.w);
        q3[0] = f2bf(qv4[3][0] + fb43.x); q3[1] = f2bf(qv4[3][1] + fb43.y);
        q3[2] = f2bf(qv4[3][2] + fb43.z); q3[3] = f2bf(qv4[3][3] + fb43.w);
        *(short4v*)&q_lds[tw0 + lo16][ 0 + g * 4] = q0;
        *(short4v*)&q_lds[tw0 + lo16][16 + g * 4] = q1;
        *(short4v*)&q_lds[tw0 + lo16][32 + g * 4] = q2;
        *(short4v*)&q_lds[tw0 + lo16][48 + g * 4] = q3;
    }

// per-channel-tile epilogue on NAMED regs (no arrays -> no scratch)
#define EPIL_CT(CT, CREG)                                                      \
    {                                                                          \
        const int colb = (CT) * 16 + g * 4;                                    \
        const short4v qb = *(const short4v*)&q_lds[tE][colb];                  \
        float4v po;                                                            \
        po[0] = CREG[0] + bf2f(qb[0]); po[1] = CREG[1] + bf2f(qb[1]);          \
        po[2] = CREG[2] + bf2f(qb[2]); po[3] = CREG[3] + bf2f(qb[3]);          \
        if (val)                                                               \
            *(float4v*)&ptx_out[(size_t)(r0E + pE) * 64 + colb] = po;          \
        float s0 = po[0] * wn, s1 = po[1] * wn, s2 = po[2] * wn, s3 = po[3] * wn; \
        s0 += __shfl_xor(s0, 1); s1 += __shfl_xor(s1, 1);                      \
        s2 += __shfl_xor(s2, 1); s3 += __shfl_xor(s3, 1);                      \
        s0 += __shfl_xor(s0, 2); s1 += __shfl_xor(s1, 2);                      \
        s2 += __shfl_xor(s2, 2); s3 += __shfl_xor(s3, 2);                      \
        s0 += __shfl_xor(s0, 4); s1 += __shfl_xor(s1, 4);                      \
        s2 += __shfl_xor(s2, 4); s3 += __shfl_xor(s3, 4);                      \
        if (pE == 0) {                                                         \
            short4v ag;                                                        \
            ag[0] = f2bf(s0); ag[1] = f2bf(s1);                                \
            ag[2] = f2bf(s2); ag[3] = f2bf(s3);                                \
            *(short4v*)&agg_b[tE][colb] = ag;                                  \
        }                                                                      \
    }

    // ---- main loop: 8 m-tiles, depth-1 prefetch, inline epilogue ----
    #pragma unroll
    for (int mt = 0; mt < 8; ++mt) {
        short8v a0, a1;   // B operand: col = point
        a0[0] = f2bf(lb0.x); a0[1] = f2bf(lb0.y); a0[2] = f2bf(lb0.z); a0[3] = f2bf(lb0.w);
        a0[4] = f2bf(lb1.x); a0[5] = f2bf(lb1.y); a0[6] = f2bf(lb1.z); a0[7] = f2bf(lb1.w);
        a1[0] = f2bf(lb2.x); a1[1] = f2bf(lb2.y); a1[2] = f2bf(lb2.z); a1[3] = f2bf(lb2.w);
        a1[4] = f2bf(lb3.x); a1[5] = f2bf(lb3.y); a1[6] = f2bf(lb3.z); a1[7] = f2bf(lb3.w);

        if (mt < 7) {   // prefetch next tile
            const float* prow = ptx + (size_t)pgm[mt + 1] * 64 + g * 8;
            lb0 = *(const float4*)(prow);
            lb1 = *(const float4*)(prow + 4);
            lb2 = *(const float4*)(prow + 32);
            lb3 = *(const float4*)(prow + 36);
        }

        float4v z = {0.f, 0.f, 0.f, 0.f};
        float4v cc0 = mfma_bf16(b1[0][1], a1, mfma_bf16(b1[0][0], a0, z));
        float4v cc1 = mfma_bf16(b1[1][1], a1, mfma_bf16(b1[1][0], a0, z));
        float4v cc2 = mfma_bf16(b1[2][1], a1, mfma_bf16(b1[2][0], a0, z));
        float4v cc3 = mfma_bf16(b1[3][1], a1, mfma_bf16(b1[3][0], a0, z));
        float4v cc4 = mfma_bf16(b1[4][1], a1, mfma_bf16(b1[4][0], a0, z));

        // lane owns point pE of target tE; logit = cc4[0] (rows identical)
        const int tE   = tw0 + mt * 2 + (lo16 >> 3);
        const int degE = deg_s[tE];
        const int r0E  = r0_s[tE];
        const int pE   = lo16 & 7;
        const bool val = (pE < degE);

        float lg = val ? cc4[0] : -3.4e38f;
        float mx = lg;
        mx = fmaxf(mx, __shfl_xor(mx, 1));
        mx = fmaxf(mx, __shfl_xor(mx, 2));
        mx = fmaxf(mx, __shfl_xor(mx, 4));
        float e = val ? __expf(lg - mx) : 0.0f;
        float sm = e;
        sm += __shfl_xor(sm, 1);
        sm += __shfl_xor(sm, 2);
        sm += __shfl_xor(sm, 4);
        const float wn = e / (sm + 1e-16f);

        EPIL_CT(0, cc0)
        EPIL_CT(1, cc1)
        EPIL_CT(2, cc2)
        EPIL_CT(3, cc3)
    }
#undef EPIL_CT

    // ---- xout write-back: agg rows wave-private -> no barrier ----
    {
        const int tgt = tid >> 2, q4 = tid & 3;
        if (t0 + tgt < n_tgt) {
            const int pix = pix_s[tgt];
            float* xp = xout + (size_t)(q4 * 16) * hw + pix;
            #pragma unroll
            for (int u = 0; u < 4; ++u) {
                short4v v = *(const short4v*)&agg_b[tgt][q4 * 16 + u * 4];
                xp[(size_t)(u * 4 + 0) * hw] = bf2f(v[0]);
                xp[(size_t)(u * 4 + 1) * hw] = bf2f(v[1]);
                xp[(size_t)(u * 4 + 2) * hw] = bf2f(v[2]);
                xp[(size_t)(u * 4 + 3) * hw] = bf2f(v[3]);
            }
        }
    }
}

extern "C" void kernel_launch(void* const* d_in, const int* in_sizes, int n_in,
                              void* d_out, int out_size, void* d_ws, size_t ws_size,
                              hipStream_t stream) {
    const float* x             = (const float*)d_in[0];
    const float* ptx           = (const float*)d_in[1];
    const float* sm_w          = (const float*)d_in[2];
    // d_in[3] = sm_b: segment-constant logit shift, cancels in softmax
    const float* fo_w          = (const float*)d_in[4];
    const float* fo_b          = (const float*)d_in[5];
    const int*   point_key     = (const int*)d_in[6];
    const int*   pixel_tgt_idx = (const int*)d_in[7];

    const int x_elems = in_sizes[0];          // 64 * H * W
    const int hw      = x_elems / 64;
    const int n_tgt   = in_sizes[7];
    const int n_pts   = in_sizes[1] / 64;

    float* xout    = (float*)d_out;
    float* ptx_out = xout + (size_t)x_elems;

    prep_w_kernel<<<5, 256, 0, stream>>>(fo_w, sm_w, (unsigned short*)d_ws);

    const int fusedBlocks = (n_tgt + TB - 1) / TB;
    const int q4n = hw / 4;
    const bool maskOK = (ws_size >= (size_t)WS_MASK_OFF + (size_t)hw) && ((hw & 3) == 0);

    if (maskOK) {
        unsigned char* mask = (unsigned char*)d_ws + WS_MASK_OFF;
        hipMemsetAsync(mask, 0, (size_t)hw, stream);
        mask_set_kernel<<<(n_tgt + 255) / 256, 256, 0, stream>>>(
            pixel_tgt_idx, mask, n_tgt);
        const int copyBlocks = (q4n + 255) / 256;
        fused_kernel<<<fusedBlocks + copyBlocks, 256, 0, stream>>>(
            x, ptx, (const unsigned short*)d_ws, fo_b, point_key, pixel_tgt_idx,
            xout, ptx_out, (const unsigned int*)mask,
            n_tgt, n_pts, hw, q4n, fusedBlocks);
    } else {
        const int n4 = x_elems / 4;
        copy_x_kernel<<<(n4 + 255) / 256, 256, 0, stream>>>(
            (const float4v*)x, (float4v*)xout, n4);
        fused_kernel<<<fusedBlocks, 256, 0, stream>>>(
            x, ptx, (const unsigned short*)d_ws, fo_b, point_key, pixel_tgt_idx,
            xout, ptx_out, (const unsigned int*)d_ws,
            n_tgt, n_pts, hw, q4n, fusedBlocks);
    }
}

// Round 15
// 138.175 us; speedup vs baseline: 1.2608x; 1.0175x over previous
//
#include <hip/hip_runtime.h>
#include <hip/hip_bf16.h>
#include <math.h>

typedef __attribute__((ext_vector_type(8))) short short8v;
typedef __attribute__((ext_vector_type(4))) short short4v;
typedef __attribute__((ext_vector_type(4))) float float4v;

#define TB 64            // targets per fused block (4 waves x 16 targets)
#define WS_MASK_OFF 32768

__device__ __forceinline__ short f2bf(float f) {
    __hip_bfloat16 h = __float2bfloat16(f);
    short s; __builtin_memcpy(&s, &h, sizeof(short));
    return s;
}
__device__ __forceinline__ float bf2f(short u) {
    unsigned int x = ((unsigned int)(unsigned short)u) << 16;
    float f; __builtin_memcpy(&f, &x, sizeof(float));
    return f;
}
__device__ __forceinline__ float4v mfma_bf16(short8v a, short8v b, float4v c) {
    return __builtin_amdgcn_mfma_f32_16x16x32_bf16(a, b, c, 0, 0, 0);
}

__global__ __launch_bounds__(256)
void mask_set_kernel(const int* __restrict__ idx, unsigned char* __restrict__ mask, int n) {
    int i = blockIdx.x * blockDim.x + threadIdx.x;
    if (i < n) mask[idx[i]] = 1;
}

// Fallback full copy (used only if d_ws is too small for the mask).
__global__ __launch_bounds__(256)
void copy_x_kernel(const float4v* __restrict__ x, float4v* __restrict__ out, int n4) {
    int i = blockIdx.x * blockDim.x + threadIdx.x;
    if (i < n4) out[i] = x[i];
}

// Precompute ALL MFMA weight fragments in per-lane order -> d_ws (bf16).
// 18 fragments x 64 lanes x 8 u16 = 18432 B (mask lives at WS_MASK_OFF).
__global__ __launch_bounds__(256)
void prep_w_kernel(const float* __restrict__ fo_w, const float* __restrict__ sm_w,
                   unsigned short* __restrict__ ws) {
    int t = blockIdx.x * 256 + threadIdx.x;
    if (t >= 18 * 64) return;
    const int frag = t >> 6, lane = t & 63;
    const int lo16 = lane & 15, g = lane >> 4;
    short8v v;
    if (frag < 16) {
        const int isB2 = frag >> 3, f = frag & 7;
        const int ct = f >> 1, kh = f & 1;
        const int kbase = isB2 * 64 + kh * 32 + g * 8;
        const int col = ct * 16 + lo16;
        #pragma unroll
        for (int j = 0; j < 8; ++j)
            v[j] = f2bf(fo_w[(size_t)(kbase + j) * 64 + col]);
    } else {
        const int kh = frag & 1;
        #pragma unroll
        for (int j = 0; j < 8; ++j)
            v[j] = f2bf(sm_w[kh * 32 + g * 8 + j]);
    }
    *(short8v*)&ws[(size_t)t * 8] = v;
}

// MERGED kernel: blocks [0, fusedBlocks) = fused segment-softmax+MLP;
// blocks >= fusedBlocks copy x->xout for NON-covered pixel quads.
// r15: DEPTH-2 prefetch WITH UNCLAMPED launch_bounds. r10's depth-2 failure
// was confounded: (256,4) clamped VGPR to 64 < ~80 live -> spill. Unclamped,
// the compiler may allocate ~100 VGPR (still >=4 waves/SIMD). Little's-law:
// the kernel sustains only 2.6TB/s because each wave keeps ~4KB in flight
// ~1/3 of the time; depth-2 doubles sustained in-flight bytes per wave.
// Fused structure (r7 best): OPERAND-SWAPPED MFMA (A=weights, B=points ->
// lane holds 4 consecutive channels of ONE point: dwordx4 stores, 1 exp/lane,
// octet-butterfly softmax). feat_px logit part + sm_b cancel in segment
// softmax. ptx_out = ptx@W1 + q[t], q = fpx@W2 + fo_b (bf16 in LDS).
// r12: no nontemporal stores (evict-first amplified partial-line writebacks).
__global__ __launch_bounds__(256)
void fused_kernel(const float* __restrict__ x,
                  const float* __restrict__ ptx,
                  const unsigned short* __restrict__ ws,
                  const float* __restrict__ fo_b,
                  const int* __restrict__ point_key,
                  const int* __restrict__ pixel_tgt_idx,
                  float* __restrict__ xout,
                  float* __restrict__ ptx_out,
                  const unsigned int* __restrict__ mask4,
                  int n_tgt, int n_pts, int hw, int q4n, int fusedBlocks)
{
    __shared__ __align__(16) unsigned short sraw[64 * 72];
    __shared__ __align__(16) unsigned short agg_b[64][72];
    __shared__ int pix_s[TB], r0_s[TB], deg_s[TB];
    unsigned short (*fpx)[72]   = (unsigned short (*)[72])sraw;
    unsigned short (*q_lds)[72] = (unsigned short (*)[72])sraw;

    const int tid = threadIdx.x;

    // ---- copy blocks: masked x->xout for uncovered quads (overlaps fused) ----
    if ((int)blockIdx.x >= fusedBlocks) {
        const int i = (blockIdx.x - fusedBlocks) * 256 + tid;
        if (i < q4n && mask4[i] != 0x01010101u) {
            const float4v* x4 = (const float4v*)x;
            float4v* o4 = (float4v*)xout;
            #pragma unroll 4
            for (int c = 0; c < 64; ++c)
                o4[(size_t)c * q4n + i] = x4[(size_t)c * q4n + i];
        }
        return;
    }

    const int lane = tid & 63;
    const int w    = tid >> 6;
    const int lo16 = lane & 15;
    const int g    = lane >> 4;
    const int t0   = blockIdx.x * TB;
    const int tw0  = w * 16;              // wave's first local target

    // ---- S0: metadata — the ONLY cross-wave LDS dependency ----
    if (tid < TB) {
        int t = t0 + tid;
        bool v = t < n_tgt;
        int r0 = v ? point_key[t] : 0;
        int d  = v ? (point_key[t + 1] - r0) : 0;
        pix_s[tid] = v ? pixel_tgt_idx[t] : 0;
        r0_s[tid]  = r0;
        deg_s[tid] = d > 8 ? 8 : d;
    }
    __syncthreads();   // meta visible; everything below is wave-private

    // ---- pgm: point-row indices for all 8 m-tiles ----
    int pgm[8];
    #pragma unroll
    for (int mt = 0; mt < 8; ++mt) {
        int tlA = tw0 + mt * 2 + (lo16 >> 3);
        int pg  = r0_s[tlA] + (lo16 & 7);
        pgm[mt] = pg < n_pts ? pg : n_pts - 1;
    }

    // ---- first TWO point-tile loads (depth-2), covered by gather + q-GEMM ----
    float4 cb0, cb1, cb2, cb3, nb0, nb1, nb2, nb3;
    {
        const float* prow = ptx + (size_t)pgm[0] * 64 + g * 8;
        cb0 = *(const float4*)(prow);
        cb1 = *(const float4*)(prow + 4);
        cb2 = *(const float4*)(prow + 32);
        cb3 = *(const float4*)(prow + 36);
        const float* prow1 = ptx + (size_t)pgm[1] * 64 + g * 8;
        nb0 = *(const float4*)(prow1);
        nb1 = *(const float4*)(prow1 + 4);
        nb2 = *(const float4*)(prow1 + 32);
        nb3 = *(const float4*)(prow1 + 36);
    }

    // ---- fpx gather (4 threads/target, coalesced per channel plane) ----
    {
        const int tgt = tid >> 2, q4 = tid & 3;
        const int pix = pix_s[tgt];
        const float* xp = x + (size_t)(q4 * 16) * hw + pix;
        #pragma unroll
        for (int hhalf = 0; hhalf < 2; ++hhalf) {
            short8v pk;
            #pragma unroll
            for (int j = 0; j < 8; ++j)
                pk[j] = f2bf(xp[(size_t)(hhalf * 8 + j) * hw]);
            *(short8v*)&fpx[tgt][q4 * 16 + hhalf * 8] = pk;
        }
    }

    // ---- weight fragments from d_ws: 10x coalesced 16B loads ----
    short8v b1[5][2];
    #pragma unroll
    for (int ct = 0; ct < 4; ++ct)
        #pragma unroll
        for (int kh = 0; kh < 2; ++kh)
            b1[ct][kh] = *(const short8v*)&ws[(size_t)((ct * 2 + kh) * 64 + lane) * 8];
    #pragma unroll
    for (int kh = 0; kh < 2; ++kh)
        b1[4][kh] = *(const short8v*)&ws[(size_t)((16 + kh) * 64 + lane) * 8];
    __syncthreads();   // fpx visible (wave-private, but keep ds-order safe)

    // ---- q-GEMM (A = W2 from ws, B = fpx cols); wave-private fpx rows ----
    float4v qv4[4];
    {
        short8v a20 = *(const short8v*)&fpx[tw0 + lo16][g * 8];
        short8v a21 = *(const short8v*)&fpx[tw0 + lo16][32 + g * 8];
        #pragma unroll
        for (int ct = 0; ct < 4; ++ct) {
            short8v b20 = *(const short8v*)&ws[(size_t)((8 + ct * 2 + 0) * 64 + lane) * 8];
            short8v b21 = *(const short8v*)&ws[(size_t)((8 + ct * 2 + 1) * 64 + lane) * 8];
            float4v z = {0.f, 0.f, 0.f, 0.f};
            z = mfma_bf16(b20, a20, z);
            qv4[ct] = mfma_bf16(b21, a21, z);
        }
    }
    // park q as bf16 over fpx (wave-private rows; ds ops in wave order)
    {
        float4 fb40 = *(const float4*)&fo_b[ 0 + g * 4];
        float4 fb41 = *(const float4*)&fo_b[16 + g * 4];
        float4 fb42 = *(const float4*)&fo_b[32 + g * 4];
        float4 fb43 = *(const float4*)&fo_b[48 + g * 4];
        short4v q0, q1, q2, q3;
        q0[0] = f2bf(qv4[0][0] + fb40.x); q0[1] = f2bf(qv4[0][1] + fb40.y);
        q0[2] = f2bf(qv4[0][2] + fb40.z); q0[3] = f2bf(qv4[0][3] + fb40.w);
        q1[0] = f2bf(qv4[1][0] + fb41.x); q1[1] = f2bf(qv4[1][1] + fb41.y);
        q1[2] = f2bf(qv4[1][2] + fb41.z); q1[3] = f2bf(qv4[1][3] + fb41.w);
        q2[0] = f2bf(qv4[2][0] + fb42.x); q2[1] = f2bf(qv4[2][1] + fb42.y);
        q2[2] = f2bf(qv4[2][2] + fb42.z); q2[3] = f2bf(qv4[2][3] + fb42.w);
        q3[0] = f2bf(qv4[3][0] + fb43.x); q3[1] = f2bf(qv4[3][1] + fb43.y);
        q3[2] = f2bf(qv4[3][2] + fb43.z); q3[3] = f2bf(qv4[3][3] + fb43.w);
        *(short4v*)&q_lds[tw0 + lo16][ 0 + g * 4] = q0;
        *(short4v*)&q_lds[tw0 + lo16][16 + g * 4] = q1;
        *(short4v*)&q_lds[tw0 + lo16][32 + g * 4] = q2;
        *(short4v*)&q_lds[tw0 + lo16][48 + g * 4] = q3;
    }

// per-channel-tile epilogue on NAMED regs (no arrays -> no scratch)
#define EPIL_CT(CT, CREG)                                                      \
    {                                                                          \
        const int colb = (CT) * 16 + g * 4;                                    \
        const short4v qb = *(const short4v*)&q_lds[tE][colb];                  \
        float4v po;                                                            \
        po[0] = CREG[0] + bf2f(qb[0]); po[1] = CREG[1] + bf2f(qb[1]);          \
        po[2] = CREG[2] + bf2f(qb[2]); po[3] = CREG[3] + bf2f(qb[3]);          \
        if (val)                                                               \
            *(float4v*)&ptx_out[(size_t)(r0E + pE) * 64 + colb] = po;          \
        float s0 = po[0] * wn, s1 = po[1] * wn, s2 = po[2] * wn, s3 = po[3] * wn; \
        s0 += __shfl_xor(s0, 1); s1 += __shfl_xor(s1, 1);                      \
        s2 += __shfl_xor(s2, 1); s3 += __shfl_xor(s3, 1);                      \
        s0 += __shfl_xor(s0, 2); s1 += __shfl_xor(s1, 2);                      \
        s2 += __shfl_xor(s2, 2); s3 += __shfl_xor(s3, 2);                      \
        s0 += __shfl_xor(s0, 4); s1 += __shfl_xor(s1, 4);                      \
        s2 += __shfl_xor(s2, 4); s3 += __shfl_xor(s3, 4);                      \
        if (pE == 0) {                                                         \
            short4v ag;                                                        \
            ag[0] = f2bf(s0); ag[1] = f2bf(s1);                                \
            ag[2] = f2bf(s2); ag[3] = f2bf(s3);                                \
            *(short4v*)&agg_b[tE][colb] = ag;                                  \
        }                                                                      \
    }

    // ---- main loop: 8 m-tiles, DEPTH-2 prefetch, inline epilogue ----
    #pragma unroll
    for (int mt = 0; mt < 8; ++mt) {
        short8v a0, a1;   // B operand: col = point
        a0[0] = f2bf(cb0.x); a0[1] = f2bf(cb0.y); a0[2] = f2bf(cb0.z); a0[3] = f2bf(cb0.w);
        a0[4] = f2bf(cb1.x); a0[5] = f2bf(cb1.y); a0[6] = f2bf(cb1.z); a0[7] = f2bf(cb1.w);
        a1[0] = f2bf(cb2.x); a1[1] = f2bf(cb2.y); a1[2] = f2bf(cb2.z); a1[3] = f2bf(cb2.w);
        a1[4] = f2bf(cb3.x); a1[5] = f2bf(cb3.y); a1[6] = f2bf(cb3.z); a1[7] = f2bf(cb3.w);

        cb0 = nb0; cb1 = nb1; cb2 = nb2; cb3 = nb3;
        if (mt < 6) {   // prefetch tile mt+2: two iterations of latency cover
            const float* prow = ptx + (size_t)pgm[mt + 2] * 64 + g * 8;
            nb0 = *(const float4*)(prow);
            nb1 = *(const float4*)(prow + 4);
            nb2 = *(const float4*)(prow + 32);
            nb3 = *(const float4*)(prow + 36);
        }

        float4v z = {0.f, 0.f, 0.f, 0.f};
        float4v cc0 = mfma_bf16(b1[0][1], a1, mfma_bf16(b1[0][0], a0, z));
        float4v cc1 = mfma_bf16(b1[1][1], a1, mfma_bf16(b1[1][0], a0, z));
        float4v cc2 = mfma_bf16(b1[2][1], a1, mfma_bf16(b1[2][0], a0, z));
        float4v cc3 = mfma_bf16(b1[3][1], a1, mfma_bf16(b1[3][0], a0, z));
        float4v cc4 = mfma_bf16(b1[4][1], a1, mfma_bf16(b1[4][0], a0, z));

        // lane owns point pE of target tE; logit = cc4[0] (rows identical)
        const int tE   = tw0 + mt * 2 + (lo16 >> 3);
        const int degE = deg_s[tE];
        const int r0E  = r0_s[tE];
        const int pE   = lo16 & 7;
        const bool val = (pE < degE);

        float lg = val ? cc4[0] : -3.4e38f;
        float mx = lg;
        mx = fmaxf(mx, __shfl_xor(mx, 1));
        mx = fmaxf(mx, __shfl_xor(mx, 2));
        mx = fmaxf(mx, __shfl_xor(mx, 4));
        float e = val ? __expf(lg - mx) : 0.0f;
        float sm = e;
        sm += __shfl_xor(sm, 1);
        sm += __shfl_xor(sm, 2);
        sm += __shfl_xor(sm, 4);
        const float wn = e / (sm + 1e-16f);

        EPIL_CT(0, cc0)
        EPIL_CT(1, cc1)
        EPIL_CT(2, cc2)
        EPIL_CT(3, cc3)
    }
#undef EPIL_CT

    // ---- xout write-back: agg rows wave-private -> no barrier ----
    {
        const int tgt = tid >> 2, q4 = tid & 3;
        if (t0 + tgt < n_tgt) {
            const int pix = pix_s[tgt];
            float* xp = xout + (size_t)(q4 * 16) * hw + pix;
            #pragma unroll
            for (int u = 0; u < 4; ++u) {
                short4v v = *(const short4v*)&agg_b[tgt][q4 * 16 + u * 4];
                xp[(size_t)(u * 4 + 0) * hw] = bf2f(v[0]);
                xp[(size_t)(u * 4 + 1) * hw] = bf2f(v[1]);
                xp[(size_t)(u * 4 + 2) * hw] = bf2f(v[2]);
                xp[(size_t)(u * 4 + 3) * hw] = bf2f(v[3]);
            }
        }
    }
}

extern "C" void kernel_launch(void* const* d_in, const int* in_sizes, int n_in,
                              void* d_out, int out_size, void* d_ws, size_t ws_size,
                              hipStream_t stream) {
    const float* x             = (const float*)d_in[0];
    const float* ptx           = (const float*)d_in[1];
    const float* sm_w          = (const float*)d_in[2];
    // d_in[3] = sm_b: segment-constant logit shift, cancels in softmax
    const float* fo_w          = (const float*)d_in[4];
    const float* fo_b          = (const float*)d_in[5];
    const int*   point_key     = (const int*)d_in[6];
    const int*   pixel_tgt_idx = (const int*)d_in[7];

    const int x_elems = in_sizes[0];          // 64 * H * W
    const int hw      = x_elems / 64;
    const int n_tgt   = in_sizes[7];
    const int n_pts   = in_sizes[1] / 64;

    float* xout    = (float*)d_out;
    float* ptx_out = xout + (size_t)x_elems;

    prep_w_kernel<<<5, 256, 0, stream>>>(fo_w, sm_w, (unsigned short*)d_ws);

    const int fusedBlocks = (n_tgt + TB - 1) / TB;
    const int q4n = hw / 4;
    const bool maskOK = (ws_size >= (size_t)WS_MASK_OFF + (size_t)hw) && ((hw & 3) == 0);

    if (maskOK) {
        unsigned char* mask = (unsigned char*)d_ws + WS_MASK_OFF;
        hipMemsetAsync(mask, 0, (size_t)hw, stream);
        mask_set_kernel<<<(n_tgt + 255) / 256, 256, 0, stream>>>(
            pixel_tgt_idx, mask, n_tgt);
        const int copyBlocks = (q4n + 255) / 256;
        fused_kernel<<<fusedBlocks + copyBlocks, 256, 0, stream>>>(
            x, ptx, (const unsigned short*)d_ws, fo_b, point_key, pixel_tgt_idx,
            xout, ptx_out, (const unsigned int*)mask,
            n_tgt, n_pts, hw, q4n, fusedBlocks);
    } else {
        const int n4 = x_elems / 4;
        copy_x_kernel<<<(n4 + 255) / 256, 256, 0, stream>>>(
            (const float4v*)x, (float4v*)xout, n4);
        fused_kernel<<<fusedBlocks, 256, 0, stream>>>(
            x, ptx, (const unsigned short*)d_ws, fo_b, point_key, pixel_tgt_idx,
            xout, ptx_out, (const unsigned int*)d_ws,
            n_tgt, n_pts, hw, q4n, fusedBlocks);
    }
}